// Round 6
// baseline (108.594 us; speedup 1.0000x reference)
//
#include <hip/hip_runtime.h>
#include <hip/hip_bf16.h>

// B=16384 rows of logits[B,4096]; prototypes[4096,768]; boundaries[4096]
#define NB 16384
#define NC 4096
#define ND 768
#define NT 32              // 4096/128 tiles per dim
#define NIC 528            // NT*(NT+1)/2 upper-triangle tile pairs (symmetry)
#define CE_BLOCKS 2048     // 8 logits rows per block + 2 prototype rows (prep)

// ws layout:
//   [0]  double acc_ce; [8] double acc_ic; [16] uint counter;  (memset 64B/call)
//   [64] float t1[4096]
//   [16448] ushort P16[4096*768]
#define WS_T1  64
#define WS_P16 16448

// LESSON (R2/R3): fusing CE+IC into ONE kernel merges register pressure ->
// scratch spills -> 11-19x loss. Keep them separate kernels.
// LESSON (R5): neither CE shape nor IC tile count moves the total; suspected
// cost is per-dispatch boundaries -> this round: 4 kernels -> 2 (+memset).

typedef __bf16 bf16x8 __attribute__((ext_vector_type(8)));
typedef float  f32x4  __attribute__((ext_vector_type(4)));

__device__ __forceinline__ unsigned short f2bf(float f) {
    return __builtin_bit_cast(unsigned short, __float2bfloat16(f));
}

// -------- CE (+ inline prototype prep): 2048 blocks ------------------------
// Phase A: waves 0-1 convert prototype rows 2b, 2b+1 to bf16 + write t1.
// Phase B: each wave does exact two-pass logsumexp on 2 logits rows,
//          fully register-resident (16 float4/lane), no syncthreads.
template<bool PRECONV>
__global__ __launch_bounds__(256) void ce_kernel(const float* __restrict__ logits,
                                                 const int* __restrict__ targets,
                                                 const float* __restrict__ prot,
                                                 const float* __restrict__ bnd,
                                                 float* __restrict__ t1,
                                                 unsigned short* __restrict__ P16,
                                                 double* __restrict__ acc_ce) {
    const int tid = threadIdx.x;
    const int w = tid >> 6, lane = tid & 63;
    const int b = blockIdx.x;

    // ---- phase A: prototype prep (2 rows per block, 1 per wave) ----
    if (w < 2) {
        const int prow = b * 2 + w;
        const float4* rp = reinterpret_cast<const float4*>(prot + (size_t)prow * ND);
        float ss = 0.f;
#pragma unroll
        for (int it = 0; it < 3; ++it) {
            int idx = it * 64 + lane;        // 192 float4 per row
            float4 v = rp[idx];
            ss += v.x * v.x + v.y * v.y + v.z * v.z + v.w * v.w;
            if (PRECONV) {
                ushort4 h;
                h.x = f2bf(v.x); h.y = f2bf(v.y); h.z = f2bf(v.z); h.w = f2bf(v.w);
                *reinterpret_cast<ushort4*>(P16 + (size_t)prow * ND + idx * 4) = h;
            }
        }
#pragma unroll
        for (int off = 32; off; off >>= 1) ss += __shfl_xor(ss, off);
        if (lane == 0) t1[prow] = (1.f - bnd[prow]) * ss;
    }

    // ---- phase B: cross-entropy, 2 rows per wave ----
    float wave_nll = 0.f;
#pragma unroll
    for (int r = 0; r < 2; ++r) {
        const int row = b * 8 + w * 2 + r;
        const int t = targets[row];                               // broadcast
        const float4* rp = reinterpret_cast<const float4*>(logits + (size_t)row * NC);
        const float xt = logits[(size_t)row * NC + t];            // issued early
        float4 v[16];
#pragma unroll
        for (int k = 0; k < 16; ++k) v[k] = rp[lane + 64 * k];    // coalesced 1KB/instr
        float m = -3.4e38f;
#pragma unroll
        for (int k = 0; k < 16; ++k)
            m = fmaxf(m, fmaxf(fmaxf(v[k].x, v[k].y), fmaxf(v[k].z, v[k].w)));
#pragma unroll
        for (int off = 32; off; off >>= 1) m = fmaxf(m, __shfl_xor(m, off));
        float s = 0.f;
#pragma unroll
        for (int k = 0; k < 16; ++k)
            s += __expf(v[k].x - m) + __expf(v[k].y - m) + __expf(v[k].z - m) + __expf(v[k].w - m);
#pragma unroll
        for (int off = 32; off; off >>= 1) s += __shfl_xor(s, off);
        wave_nll += m + __logf(s) - xt;
    }
    __shared__ float wp[4];
    if (lane == 0) wp[w] = wave_nll;
    __syncthreads();
    if (tid == 0)
        atomicAdd(acc_ce, (double)((wp[0] + wp[1]) + (wp[2] + wp[3])));
}

// -------- IC: symmetric 128x128 Gram tiles + last-block finalize -----------
template<bool PRECONV>
__global__ __launch_bounds__(256) void ic_kernel(const unsigned short* __restrict__ P16,
                                                 const float* __restrict__ prot,
                                                 const float* __restrict__ bnd,
                                                 const float* __restrict__ t1,
                                                 double* __restrict__ acc_ce,
                                                 double* __restrict__ acc_ic,
                                                 unsigned int* __restrict__ cnt,
                                                 float* __restrict__ out) {
    __shared__ __bf16 As[128][72];
    __shared__ __bf16 Bs[128][72];
    const int tid = threadIdx.x;

    const int icid = blockIdx.x;
    int u = icid, bi = 0;
    while (u >= NT - bi) { u -= NT - bi; ++bi; }
    const int bj = bi + u;
    const bool diag = (bi == bj);
    const int row0 = bi * 128, col0 = bj * 128;

    const int lane = tid & 63, w = tid >> 6;
    const int fr = lane & 15, fq = lane >> 4;
    const int wrow = (w >> 1) * 64, wcol = (w & 1) * 64;

    f32x4 acc[4][4];
#pragma unroll
    for (int mi = 0; mi < 4; ++mi)
#pragma unroll
        for (int nj = 0; nj < 4; ++nj) acc[mi][nj] = (f32x4){0.f, 0.f, 0.f, 0.f};

    for (int kt = 0; kt < ND / 64; ++kt) {
        if (PRECONV) {
#pragma unroll
            for (int s2 = 0; s2 < 4; ++s2) {
                int c = tid + 256 * s2;          // 1024 chunks of 8 bf16 per tile
                int r = c >> 3, k8 = c & 7;
                uint4 va = *reinterpret_cast<const uint4*>(P16 + (size_t)(row0 + r) * ND + kt * 64 + k8 * 8);
                *reinterpret_cast<uint4*>(&As[r][k8 * 8]) = va;
                uint4 vb = *reinterpret_cast<const uint4*>(P16 + (size_t)(col0 + r) * ND + kt * 64 + k8 * 8);
                *reinterpret_cast<uint4*>(&Bs[r][k8 * 8]) = vb;
            }
        } else {
#pragma unroll
            for (int s2 = 0; s2 < 8; ++s2) {
                int c = tid + 256 * s2;          // 2048 chunks of 4 floats per tile
                int r = c >> 4, k4 = c & 15;
                float4 va = *reinterpret_cast<const float4*>(prot + (size_t)(row0 + r) * ND + kt * 64 + k4 * 4);
                ushort4 ha; ha.x = f2bf(va.x); ha.y = f2bf(va.y); ha.z = f2bf(va.z); ha.w = f2bf(va.w);
                *reinterpret_cast<ushort4*>(&As[r][k4 * 4]) = ha;
                float4 vb = *reinterpret_cast<const float4*>(prot + (size_t)(col0 + r) * ND + kt * 64 + k4 * 4);
                ushort4 hb; hb.x = f2bf(vb.x); hb.y = f2bf(vb.y); hb.z = f2bf(vb.z); hb.w = f2bf(vb.w);
                *reinterpret_cast<ushort4*>(&Bs[r][k4 * 4]) = hb;
            }
        }
        __syncthreads();
#pragma unroll
        for (int ks = 0; ks < 64; ks += 32) {
            bf16x8 af[4], bfv[4];
#pragma unroll
            for (int mi = 0; mi < 4; ++mi)
                af[mi] = *reinterpret_cast<const bf16x8*>(&As[wrow + mi * 16 + fr][ks + fq * 8]);
#pragma unroll
            for (int nj = 0; nj < 4; ++nj)
                bfv[nj] = *reinterpret_cast<const bf16x8*>(&Bs[wcol + nj * 16 + fr][ks + fq * 8]);
#pragma unroll
            for (int mi = 0; mi < 4; ++mi)
#pragma unroll
                for (int nj = 0; nj < 4; ++nj)
                    acc[mi][nj] = __builtin_amdgcn_mfma_f32_16x16x32_bf16(af[mi], bfv[nj], acc[mi][nj], 0, 0, 0);
        }
        __syncthreads();
    }

    // epilogue: tij = t1[i] + (b_j-1)*G ; off-diag pairs also add the mirror
    float t1a[16], ba1[16];
#pragma unroll
    for (int mi = 0; mi < 4; ++mi)
#pragma unroll
        for (int e = 0; e < 4; ++e) {
            int i = row0 + wrow + mi * 16 + fq * 4 + e;
            t1a[mi * 4 + e] = t1[i];
            ba1[mi * 4 + e] = bnd[i] - 1.f;
        }
    float t1b[4], bb1[4];
#pragma unroll
    for (int nj = 0; nj < 4; ++nj) {
        int j = col0 + wcol + nj * 16 + fr;
        t1b[nj] = t1[j];
        bb1[nj] = bnd[j] - 1.f;
    }

    float sum = 0.f;
#pragma unroll
    for (int mi = 0; mi < 4; ++mi) {
#pragma unroll
        for (int nj = 0; nj < 4; ++nj) {
#pragma unroll
            for (int e = 0; e < 4; ++e) {
                float G = acc[mi][nj][e];
                float tij = t1a[mi * 4 + e] + bb1[nj] * G;     // (i in A, j in B)
                if (diag) {
                    int il = wrow + mi * 16 + fq * 4 + e;
                    int jl = wcol + nj * 16 + fr;
                    if (il != jl) sum += fmaxf(tij, 0.f);
                } else {
                    float tji = t1b[nj] + ba1[mi * 4 + e] * G; // mirrored order
                    sum += fmaxf(tij, 0.f) + fmaxf(tji, 0.f);
                }
            }
        }
    }
#pragma unroll
    for (int off = 32; off; off >>= 1) sum += __shfl_xor(sum, off);
    __shared__ float redf[4];
    if (lane == 0) redf[w] = sum;
    __syncthreads();

    // last-finished block folds both accumulators and writes the 3 outputs
    if (tid == 0) {
        atomicAdd(acc_ic, (double)(redf[0] + redf[1] + redf[2] + redf[3]));
        __threadfence();
        unsigned int old = atomicAdd(cnt, 1u);
        if (old == NIC - 1) {
            __threadfence();
            double ce_sum = atomicAdd(acc_ce, 0.0);   // device-coherent reads
            double ic_sum = atomicAdd(acc_ic, 0.0);
            double cls = ce_sum / (double)NB;
            double ic  = ic_sum / ((double)NC * (double)(NC - 1));
            out[0] = (float)(cls + 0.05 * ic);
            out[1] = (float)cls;
            out[2] = (float)ic;
        }
    }
}

extern "C" void kernel_launch(void* const* d_in, const int* in_sizes, int n_in,
                              void* d_out, int out_size, void* d_ws, size_t ws_size,
                              hipStream_t stream) {
    const float* logits  = (const float*)d_in[0];
    const int*   targets = (const int*)d_in[1];
    const float* prot    = (const float*)d_in[2];
    const float* bnd     = (const float*)d_in[3];
    float* out = (float*)d_out;
    char* ws = (char*)d_ws;
    double* acc_ce = (double*)(ws + 0);
    double* acc_ic = (double*)(ws + 8);
    unsigned int* cnt = (unsigned int*)(ws + 16);
    float* t1 = (float*)(ws + WS_T1);
    unsigned short* P16 = (unsigned short*)(ws + WS_P16);
    bool pre = ws_size >= (size_t)WS_P16 + 2ull * NC * ND;

    hipMemsetAsync(ws, 0, 64, stream);   // ctl state (graph-capturable node)
    if (pre) {
        ce_kernel<true><<<CE_BLOCKS, 256, 0, stream>>>(logits, targets, prot, bnd, t1, P16, acc_ce);
        ic_kernel<true><<<NIC, 256, 0, stream>>>(P16, prot, bnd, t1, acc_ce, acc_ic, cnt, out);
    } else {
        ce_kernel<false><<<CE_BLOCKS, 256, 0, stream>>>(logits, targets, prot, bnd, t1, nullptr, acc_ce);
        ic_kernel<false><<<NIC, 256, 0, stream>>>(nullptr, prot, bnd, t1, acc_ce, acc_ic, cnt, out);
    }
}